// Round 3
// baseline (1962.666 us; speedup 1.0000x reference)
//
#include <hip/hip_runtime.h>
#include <hip/hip_bf16.h>

#define NB 2
#define TT 16
#define SS 196
#define DD 768
#define NHEADS 12
#define HD 64
#define TOK (NB*TT*SS)        // 6272 tokens
#define QPN (TT*SS)           // 3136 queries per batch
#define KPN (TT*(SS/2))       // 1568 keys per batch
#define SCALE 0.125f

typedef _Float16 f16;
typedef _Float16 f16x8 __attribute__((ext_vector_type(8)));
typedef _Float16 f16x4 __attribute__((ext_vector_type(4)));
typedef float    f32x4 __attribute__((ext_vector_type(4)));

// ---------------- cast fp32 -> fp16 ----------------
__global__ void cast_f32_to_f16(const float* __restrict__ in, f16* __restrict__ out, int n4) {
    int i = blockIdx.x * blockDim.x + threadIdx.x;
    if (i < n4) {
        float4 v = reinterpret_cast<const float4*>(in)[i];
        f16x4 h; h[0] = (f16)v.x; h[1] = (f16)v.y; h[2] = (f16)v.z; h[3] = (f16)v.w;
        reinterpret_cast<f16x4*>(out)[i] = h;
    }
}

// ---------------- transpose + cast: in fp32 [R][C] -> out f16 [C][R] ----------------
__global__ void transpose_cast(const float* __restrict__ in, f16* __restrict__ out, int R, int C) {
    __shared__ float tile[32][33];
    int c0 = blockIdx.x * 32, r0 = blockIdx.y * 32;
    int tx = threadIdx.x & 31, ty = threadIdx.x >> 5;   // 32 x 8
#pragma unroll
    for (int j = 0; j < 4; j++)
        tile[ty + 8*j][tx] = in[(size_t)(r0 + ty + 8*j) * C + c0 + tx];
    __syncthreads();
#pragma unroll
    for (int j = 0; j < 4; j++)
        out[(size_t)(c0 + ty + 8*j) * R + r0 + tx] = (f16)tile[tx][ty + 8*j];
}

// ---------------- f16 MFMA GEMM: C[M][N] = A[M][K] @ Bt[N][K]^T ----------------
// EPI 0: scatter to q/k/v fp32 (with stride-2 subsample for k,v)
// EPI 1: + bias, write fp32 to d_out
template<int EPI>
__launch_bounds__(256, 2)
__global__ void gemm_f16(const f16* __restrict__ A, const f16* __restrict__ Bt,
                         int M, int N, int K,
                         float* __restrict__ q_ws, float* __restrict__ k_ws,
                         float* __restrict__ v_ws,
                         const float* __restrict__ bias, float* __restrict__ outf) {
    __shared__ f16 As[128 * 40];   // 128 rows x 32 k, padded to 40 f16 (80B, 16B-aligned)
    __shared__ f16 Bs[128 * 40];
    int tid  = threadIdx.x;
    int lane = tid & 63, w = tid >> 6;
    int wm = w >> 1, wn = w & 1;                 // 2x2 waves, each 64x64
    int l15 = lane & 15, l4 = lane >> 4;
    int mBase = blockIdx.y * 128, nBase = blockIdx.x * 128;
    int r0 = tid >> 2, s0 = tid & 3;             // staging: row, 8-f16 segment

    f32x4 acc[4][4] = {};

    const int KT = K / 32;
    for (int kt = 0; kt < KT; kt++) {
        int k0 = kt * 32;
        *(f16x8*)&As[r0*40 + s0*8]        = *(const f16x8*)&A [(size_t)(mBase + r0     ) * K + k0 + s0*8];
        *(f16x8*)&As[(r0+64)*40 + s0*8]   = *(const f16x8*)&A [(size_t)(mBase + r0 + 64) * K + k0 + s0*8];
        *(f16x8*)&Bs[r0*40 + s0*8]        = *(const f16x8*)&Bt[(size_t)(nBase + r0     ) * K + k0 + s0*8];
        *(f16x8*)&Bs[(r0+64)*40 + s0*8]   = *(const f16x8*)&Bt[(size_t)(nBase + r0 + 64) * K + k0 + s0*8];
        __syncthreads();
        f16x8 af[4], bf[4];
#pragma unroll
        for (int i = 0; i < 4; i++) {
            af[i] = *(const f16x8*)&As[(wm*64 + i*16 + l15)*40 + l4*8];
            bf[i] = *(const f16x8*)&Bs[(wn*64 + i*16 + l15)*40 + l4*8];
        }
#pragma unroll
        for (int i = 0; i < 4; i++)
#pragma unroll
            for (int j = 0; j < 4; j++)
                acc[i][j] = __builtin_amdgcn_mfma_f32_16x16x32_f16(af[i], bf[j], acc[i][j], 0, 0, 0);
        __syncthreads();
    }

    int rbase2 = mBase + wm*64;
    int cbase2 = nBase + wn*64;
#pragma unroll
    for (int i = 0; i < 4; i++) {
#pragma unroll
        for (int j = 0; j < 4; j++) {
            int col = cbase2 + j*16 + l15;
#pragma unroll
            for (int r = 0; r < 4; r++) {
                int row = rbase2 + i*16 + l4*4 + r;
                float val = acc[i][j][r];
                if constexpr (EPI == 0) {
                    if (col < 768) {
                        q_ws[(size_t)row * 768 + col] = val;
                    } else {
                        int n = row / QPN; int rem = row - n*QPN;
                        int t = rem / SS;  int s   = rem - t*SS;
                        if (!(s & 1)) {
                            int krow = n*KPN + t*(SS/2) + (s >> 1);
                            if (col < 1536) k_ws[(size_t)krow * 768 + (col - 768)]  = val;
                            else            v_ws[(size_t)krow * 768 + (col - 1536)] = val;
                        }
                    }
                } else {
                    outf[(size_t)row * 768 + col] = val + bias[col];
                }
            }
        }
    }
}

// ---------------- attention: 1 wave per block, 1 query per lane ----------------
// fp32 VALU, per-thread online softmax, LDS K/V tiles read at uniform address (broadcast)
__launch_bounds__(64, 2)
__global__ void attn_kernel(const float* __restrict__ q_ws, const float* __restrict__ k_ws,
                            const float* __restrict__ v_ws, f16* __restrict__ attn_out) {
    int tid = threadIdx.x;
    int qt  = blockIdx.x;             // 0..48
    int nh  = blockIdx.y;             // 0..23
    int n = nh / NHEADS, h = nh - n*NHEADS;
    __shared__ float Ks[32 * 68];     // 32 keys x 64 dims, padded
    __shared__ float Vs[32 * 68];

    int qi = qt*64 + tid;             // query index within batch n
    const float* qrow = q_ws + (size_t)(n*QPN + qi) * DD + h*HD;
    f32x4 qreg[16];
#pragma unroll
    for (int i = 0; i < 16; i++) qreg[i] = *(const f32x4*)&qrow[i*4];

    f32x4 acc[16] = {};
    float M = -INFINITY, L = 0.f;
    int sr = tid >> 1, sh = tid & 1;  // staging: row, half

    for (int ktile = 0; ktile < 49; ktile++) {
        int kbase = ktile * 32;
        const float* krow = k_ws + (size_t)(n*KPN + kbase + sr) * DD + h*HD + sh*32;
        const float* vrow = v_ws + (size_t)(n*KPN + kbase + sr) * DD + h*HD + sh*32;
#pragma unroll
        for (int j = 0; j < 8; j++) {
            *(f32x4*)&Ks[sr*68 + sh*32 + j*4] = *(const f32x4*)&krow[j*4];
            *(f32x4*)&Vs[sr*68 + sh*32 + j*4] = *(const f32x4*)&vrow[j*4];
        }
        __syncthreads();

        float sarr[32];
#pragma unroll
        for (int k = 0; k < 32; k++) {
            float s = 0.f;
#pragma unroll
            for (int d = 0; d < 16; d++) {
                f32x4 kv = *(const f32x4*)&Ks[k*68 + d*4];
                s += qreg[d][0]*kv[0] + qreg[d][1]*kv[1] + qreg[d][2]*kv[2] + qreg[d][3]*kv[3];
            }
            sarr[k] = s * SCALE;
        }
        float tmax = sarr[0];
#pragma unroll
        for (int k = 1; k < 32; k++) tmax = fmaxf(tmax, sarr[k]);
        float Mnew = fmaxf(M, tmax);
        float cor = __expf(M - Mnew);   // first tile: exp(-inf) = 0
        L *= cor;
#pragma unroll
        for (int i = 0; i < 16; i++) acc[i] *= cor;
#pragma unroll
        for (int k = 0; k < 32; k++) {
            float p = __expf(sarr[k] - Mnew);
            L += p;
#pragma unroll
            for (int d = 0; d < 16; d++) {
                f32x4 vv = *(const f32x4*)&Vs[k*68 + d*4];
                acc[d] += vv * p;
            }
        }
        M = Mnew;
        __syncthreads();
    }

    float inv = 1.f / L;
    f16* orow = attn_out + (size_t)(n*QPN + qi) * DD + h*HD;
#pragma unroll
    for (int c = 0; c < 8; c++) {
        f16x8 hv;
#pragma unroll
        for (int j = 0; j < 4; j++) {
            hv[j]   = (f16)(acc[c*2][j]   * inv);
            hv[4+j] = (f16)(acc[c*2+1][j] * inv);
        }
        *(f16x8*)&orow[c*8] = hv;
    }
}

extern "C" void kernel_launch(void* const* d_in, const int* in_sizes, int n_in,
                              void* d_out, int out_size, void* d_ws, size_t ws_size,
                              hipStream_t stream) {
    const float* x      = (const float*)d_in[0];
    const float* W_qkv  = (const float*)d_in[1];
    const float* W_proj = (const float*)d_in[2];
    const float* b_proj = (const float*)d_in[3];
    float* out = (float*)d_out;

    char* ws = (char*)d_ws;
    size_t off = 0;
    auto alloc = [&](size_t bytes) { void* p = ws + off; off += (bytes + 255) & ~255ULL; return p; };
    f16*   x16    = (f16*)  alloc((size_t)TOK * DD * 2);
    f16*   WqkvT  = (f16*)  alloc((size_t)2304 * 768 * 2);
    f16*   WprojT = (f16*)  alloc((size_t)768 * 768 * 2);
    float* q_ws   = (float*)alloc((size_t)TOK * DD * 4);
    float* k_ws   = (float*)alloc((size_t)NB * KPN * DD * 4);
    float* v_ws   = (float*)alloc((size_t)NB * KPN * DD * 4);
    f16*   attn16 = (f16*)  alloc((size_t)TOK * DD * 2);
    (void)ws_size; (void)in_sizes; (void)n_in; (void)out_size;

    cast_f32_to_f16<<<(TOK*DD/4 + 255)/256, 256, 0, stream>>>(x, x16, TOK*DD/4);
    transpose_cast<<<dim3(2304/32, 768/32), 256, 0, stream>>>(W_qkv, WqkvT, 768, 2304);
    transpose_cast<<<dim3(768/32, 768/32), 256, 0, stream>>>(W_proj, WprojT, 768, 768);
    gemm_f16<0><<<dim3(2304/128, 6272/128), 256, 0, stream>>>(
        x16, WqkvT, TOK, 2304, 768, q_ws, k_ws, v_ws, nullptr, nullptr);
    attn_kernel<<<dim3(49, 24), 64, 0, stream>>>(q_ws, k_ws, v_ws, attn16);
    gemm_f16<1><<<dim3(768/128, 6272/128), 256, 0, stream>>>(
        attn16, WprojT, TOK, 768, 768, nullptr, nullptr, nullptr, b_proj, out);
}

// Round 7
// 226.398 us; speedup vs baseline: 8.6691x; 8.6691x over previous
//
#include <hip/hip_runtime.h>
#include <hip/hip_bf16.h>

#define NB 2
#define TT 16
#define SS 196
#define DD 768
#define NHEADS 12
#define HD 64
#define TOK (NB*TT*SS)        // 6272 tokens
#define QPN (TT*SS)           // 3136 queries per batch
#define KPN (TT*(SS/2))       // 1568 keys per batch

typedef _Float16 f16;
typedef _Float16 f16x4 __attribute__((ext_vector_type(4)));
typedef _Float16 f16x8 __attribute__((ext_vector_type(8)));
typedef float    f32x4 __attribute__((ext_vector_type(4)));
typedef unsigned int u32;

static __device__ __forceinline__ u32 pk16(float a, float b) {
    return __builtin_bit_cast(u32, __builtin_amdgcn_cvt_pkrtz(a, b));
}

// ---------------- cast fp32 -> fp16 ----------------
__global__ void cast_f32_to_f16(const float* __restrict__ in, f16* __restrict__ out, int n4) {
    int i = blockIdx.x * blockDim.x + threadIdx.x;
    if (i < n4) {
        float4 v = reinterpret_cast<const float4*>(in)[i];
        f16x4 h; h[0] = (f16)v.x; h[1] = (f16)v.y; h[2] = (f16)v.z; h[3] = (f16)v.w;
        reinterpret_cast<f16x4*>(out)[i] = h;
    }
}

// ---------------- transpose + cast: in fp32 [R][C] -> out f16 [C][R] ----------------
__global__ void transpose_cast(const float* __restrict__ in, f16* __restrict__ out, int R, int C) {
    __shared__ float tile[32][33];
    int c0 = blockIdx.x * 32, r0 = blockIdx.y * 32;
    int tx = threadIdx.x & 31, ty = threadIdx.x >> 5;   // 32 x 8
#pragma unroll
    for (int j = 0; j < 4; j++)
        tile[ty + 8*j][tx] = in[(size_t)(r0 + ty + 8*j) * C + c0 + tx];
    __syncthreads();
#pragma unroll
    for (int j = 0; j < 4; j++)
        out[(size_t)(c0 + ty + 8*j) * R + r0 + tx] = (f16)tile[tx][ty + 8*j];
}

// ---------------- f16 MFMA GEMM: C[M][N] = A[M][K] @ Bt[N][K]^T ----------------
// EPI 0: scatter q(f16, pre-scaled 0.125), k(f16 row-major), v(f16 TRANSPOSED per head)
// EPI 1: + bias, write fp32 to d_out
template<int EPI>
__launch_bounds__(256, 2)
__global__ void gemm_f16(const f16* __restrict__ A, const f16* __restrict__ Bt,
                         int M, int N, int K,
                         f16* __restrict__ q16, f16* __restrict__ k16,
                         f16* __restrict__ vt16,
                         const float* __restrict__ bias, float* __restrict__ outf) {
    __shared__ f16 As[128 * 40];   // 128 rows x 32 k, padded to 40 f16
    __shared__ f16 Bs[128 * 40];
    int tid  = threadIdx.x;
    int lane = tid & 63, w = tid >> 6;
    int wm = w >> 1, wn = w & 1;                 // 2x2 waves, each 64x64
    int l15 = lane & 15, l4 = lane >> 4;
    int mBase = blockIdx.y * 128, nBase = blockIdx.x * 128;
    int r0 = tid >> 2, s0 = tid & 3;             // staging: row, 8-f16 segment

    f32x4 acc[4][4] = {};

    const int KT = K / 32;
    for (int kt = 0; kt < KT; kt++) {
        int k0 = kt * 32;
        *(f16x8*)&As[r0*40 + s0*8]        = *(const f16x8*)&A [(size_t)(mBase + r0     ) * K + k0 + s0*8];
        *(f16x8*)&As[(r0+64)*40 + s0*8]   = *(const f16x8*)&A [(size_t)(mBase + r0 + 64) * K + k0 + s0*8];
        *(f16x8*)&Bs[r0*40 + s0*8]        = *(const f16x8*)&Bt[(size_t)(nBase + r0     ) * K + k0 + s0*8];
        *(f16x8*)&Bs[(r0+64)*40 + s0*8]   = *(const f16x8*)&Bt[(size_t)(nBase + r0 + 64) * K + k0 + s0*8];
        __syncthreads();
        f16x8 af[4], bf[4];
#pragma unroll
        for (int i = 0; i < 4; i++) {
            af[i] = *(const f16x8*)&As[(wm*64 + i*16 + l15)*40 + l4*8];
            bf[i] = *(const f16x8*)&Bs[(wn*64 + i*16 + l15)*40 + l4*8];
        }
#pragma unroll
        for (int i = 0; i < 4; i++)
#pragma unroll
            for (int j = 0; j < 4; j++)
                acc[i][j] = __builtin_amdgcn_mfma_f32_16x16x32_f16(af[i], bf[j], acc[i][j], 0, 0, 0);
        __syncthreads();
    }

    int rbase2 = mBase + wm*64;
    int cbase2 = nBase + wn*64;
#pragma unroll
    for (int i = 0; i < 4; i++) {
#pragma unroll
        for (int j = 0; j < 4; j++) {
            int col = cbase2 + j*16 + l15;
#pragma unroll
            for (int r = 0; r < 4; r++) {
                int row = rbase2 + i*16 + l4*4 + r;
                float val = acc[i][j][r];
                if constexpr (EPI == 0) {
                    if (col < 768) {
                        q16[(size_t)row * 768 + col] = (f16)(val * 0.125f);  // fold attn SCALE
                    } else {
                        int n = row / QPN; int rem = row - n*QPN;
                        int t = rem / SS;  int s   = rem - t*SS;
                        if (!(s & 1)) {
                            int kb = t*(SS/2) + (s >> 1);                    // key idx within batch
                            if (col < 1536) {
                                k16[(size_t)(n*KPN + kb) * 768 + (col - 768)] = (f16)val;
                            } else {
                                int c = col - 1536; int hh = c >> 6, dd = c & 63;
                                vt16[((size_t)(n*NHEADS + hh)*64 + dd) * KPN + kb] = (f16)val;
                            }
                        }
                    }
                } else {
                    outf[(size_t)row * 768 + col] = val + bias[col];
                }
            }
        }
    }
}

// ---------------- MFMA flash attention (16x16x32 only, LDS P round-trip) ----------
// Block: 256 thr = 4 waves, each wave owns 16 q-rows. Grid (49, 24). KVBLK=32.
// Swapped QK^T: S[key][q] = mfma(Kfrag, Qfrag)  (col=q=l15, row=key=l4*4+r)
// P staged to per-wave LDS [q][key], read back as PV B-frag (keys l4*8..+7).
// PV: O[d][q] = mfma(Vtfrag, Pfrag)  (col=q=l15, row=d=c*16+l4*4+r)
__launch_bounds__(256, 2)
__global__ void attn_mfma(const f16* __restrict__ q16, const f16* __restrict__ k16,
                          const f16* __restrict__ vt16, f16* __restrict__ o16) {
    int tid = threadIdx.x;
    int lane = tid & 63, w = tid >> 6;
    int qt = blockIdx.x, nh = blockIdx.y;
    int n = nh / NHEADS, h = nh - n*NHEADS;
    int l15 = lane & 15, l4 = lane >> 4;

    __shared__ f16 Klds[32 * 64];       // 32 keys x 64 d, 128B rows, XOR-swizzled
    __shared__ f16 Vtlds[64 * 40];      // 64 d x 32 keys, 80B rows
    __shared__ f16 Plds[4][16 * 40];    // per-wave: 16 q x 32 keys, 80B rows

    // staging coords (256 threads)
    int krow = tid >> 3, kseg = tid & 7;          // K: 32 rows x 8 segs of 8 f16
    u32 kwo = (u32)((krow * 128 + kseg * 16) ^ ((krow & 7) << 4));
    int vd = tid >> 2, vseg = tid & 3;            // Vt: 64 rows x 4 segs of 8 f16

    const f16* kgb = k16 + (size_t)n * KPN * 768 + h * 64;
    const f16* vgb = vt16 + ((size_t)nh * 64 + vd) * KPN;

    int qglob = n*QPN + qt*64 + w*16 + l15;
    const f16* qrow = q16 + (size_t)qglob * 768 + h*64;
    f16x8 qf0 = *(const f16x8*)&qrow[l4*8];        // B-frag: col=q=l15, k=d= l4*8+i
    f16x8 qf1 = *(const f16x8*)&qrow[32 + l4*8];   // d = 32 + l4*8+i

    f32x4 acc[4] = {};                  // acc[c][r] -> O[d=c*16+l4*4+r][q=l15]
    float M = -INFINITY, L = 0.f;

    // preload tile 0 into regs
    f16x8 stK = *(const f16x8*)&kgb[(size_t)krow * 768 + kseg*8];
    f16x8 stV = *(const f16x8*)&vgb[vseg*8];

    for (int t = 0; t < 49; t++) {
        __syncthreads();   // prev tile's K/V reads done
        *(f16x8*)((char*)Klds + kwo) = stK;
        *(f16x8*)&Vtlds[vd*40 + vseg*8] = stV;
        __syncthreads();   // tile t visible

        if (t < 48) {      // prefetch next tile (hides under compute)
            int kb = (t + 1) * 32;
            stK = *(const f16x8*)&kgb[(size_t)(kb + krow) * 768 + kseg*8];
            stV = *(const f16x8*)&vgb[kb + vseg*8];
        }

        // ---- QK^T: S[kh][r] = S[key = kh*16 + l4*4 + r][q = l15]
        f32x4 S0 = {}, S1 = {};
#pragma unroll
        for (int kh = 0; kh < 2; kh++) {
            int rowb = (kh*16 + l15) * 128;
            u32 x = (u32)((l15 & 7) << 4);
            f16x8 ka0 = *(const f16x8*)((char*)Klds + ((rowb +      l4*16) ^ x));
            f16x8 ka1 = *(const f16x8*)((char*)Klds + ((rowb + 64 + l4*16) ^ x));
            f32x4& S = kh ? S1 : S0;
            S = __builtin_amdgcn_mfma_f32_16x16x32_f16(ka0, qf0, S, 0, 0, 0);
            S = __builtin_amdgcn_mfma_f32_16x16x32_f16(ka1, qf1, S, 0, 0, 0);
        }

        // ---- online softmax for q = l15 (reduce over l4 group: lanes stride 16)
        float tm = fmaxf(fmaxf(fmaxf(S0[0], S0[1]), fmaxf(S0[2], S0[3])),
                         fmaxf(fmaxf(S1[0], S1[1]), fmaxf(S1[2], S1[3])));
        tm = fmaxf(tm, __shfl_xor(tm, 16));
        tm = fmaxf(tm, __shfl_xor(tm, 32));
        float Mnew = fmaxf(M, tm);
        float cor = __expf(M - Mnew);   // first tile: exp(-inf)=0
        float ls;
        f16* pw = &Plds[w][l15*40];
        {
            float p0 = __expf(S0[0]-Mnew), p1 = __expf(S0[1]-Mnew);
            float p2 = __expf(S0[2]-Mnew), p3 = __expf(S0[3]-Mnew);
            float p4 = __expf(S1[0]-Mnew), p5 = __expf(S1[1]-Mnew);
            float p6 = __expf(S1[2]-Mnew), p7 = __expf(S1[3]-Mnew);
            ls = ((p0+p1)+(p2+p3)) + ((p4+p5)+(p6+p7));
            uint2 pkA; pkA.x = pk16(p0, p1); pkA.y = pk16(p2, p3);
            *(uint2*)&pw[l4*4] = pkA;            // keys l4*4 + 0..3
            uint2 pkB; pkB.x = pk16(p4, p5); pkB.y = pk16(p6, p7);
            *(uint2*)&pw[16 + l4*4] = pkB;       // keys 16 + l4*4 + 0..3
        }
        ls += __shfl_xor(ls, 16);
        ls += __shfl_xor(ls, 32);
        L = L * cor + ls;
        M = Mnew;
#pragma unroll
        for (int c = 0; c < 4; c++) acc[c] *= cor;

        // ---- PV: B-frag = P[q = l15][key = l4*8 + i]  (same-wave LDS RAW; compiler waits)
        f16x8 pf = *(const f16x8*)&Plds[w][l15*40 + l4*8];
#pragma unroll
        for (int c = 0; c < 4; c++) {
            f16x8 vf = *(const f16x8*)((char*)Vtlds + (c*16 + l15)*80 + l4*16);
            acc[c] = __builtin_amdgcn_mfma_f32_16x16x32_f16(vf, pf, acc[c], 0, 0, 0);
        }
    }

    // ---- epilogue: O[q][d] = acc / L
    float inv = 1.f / L;
    f16* orow = o16 + (size_t)qglob * 768 + h*64;
#pragma unroll
    for (int c = 0; c < 4; c++) {
        uint2 o2;
        o2.x = pk16(acc[c][0]*inv, acc[c][1]*inv);
        o2.y = pk16(acc[c][2]*inv, acc[c][3]*inv);
        *(uint2*)&orow[c*16 + l4*4] = o2;
    }
}

extern "C" void kernel_launch(void* const* d_in, const int* in_sizes, int n_in,
                              void* d_out, int out_size, void* d_ws, size_t ws_size,
                              hipStream_t stream) {
    const float* x      = (const float*)d_in[0];
    const float* W_qkv  = (const float*)d_in[1];
    const float* W_proj = (const float*)d_in[2];
    const float* b_proj = (const float*)d_in[3];
    float* out = (float*)d_out;

    char* ws = (char*)d_ws;
    size_t off = 0;
    auto alloc = [&](size_t bytes) { void* p = ws + off; off += (bytes + 255) & ~255ULL; return p; };
    f16* x16    = (f16*)alloc((size_t)TOK * DD * 2);
    f16* WqkvT  = (f16*)alloc((size_t)2304 * 768 * 2);
    f16* WprojT = (f16*)alloc((size_t)768 * 768 * 2);
    f16* q16    = (f16*)alloc((size_t)TOK * DD * 2);
    f16* k16    = (f16*)alloc((size_t)NB * KPN * DD * 2);
    f16* vt16   = (f16*)alloc((size_t)NB * NHEADS * HD * KPN * 2);
    f16* o16    = (f16*)alloc((size_t)TOK * DD * 2);
    (void)ws_size; (void)in_sizes; (void)n_in; (void)out_size;

    cast_f32_to_f16<<<(TOK*DD/4 + 255)/256, 256, 0, stream>>>(x, x16, TOK*DD/4);
    transpose_cast<<<dim3(2304/32, 768/32), 256, 0, stream>>>(W_qkv, WqkvT, 768, 2304);
    transpose_cast<<<dim3(768/32, 768/32), 256, 0, stream>>>(W_proj, WprojT, 768, 768);
    gemm_f16<0><<<dim3(2304/128, 6272/128), 256, 0, stream>>>(
        x16, WqkvT, TOK, 2304, 768, q16, k16, vt16, nullptr, nullptr);
    attn_mfma<<<dim3(49, 24), 256, 0, stream>>>(q16, k16, vt16, o16);
    gemm_f16<1><<<dim3(768/128, 6272/128), 256, 0, stream>>>(
        o16, WprojT, TOK, 768, 768, nullptr, nullptr, nullptr, b_proj, out);
}